// Round 4
// baseline (131.695 us; speedup 1.0000x reference)
//
#include <hip/hip_runtime.h>
#include <hip/hip_bf16.h>

#define IN_DIM 128
#define NBLK 256   // 1 block/CU -> all blocks guaranteed co-resident (capacity >= 1/CU)
#define NTHR 256
#define MAX_GRP 3  // ceil(156250 / 65536)

// Fused persistent kernel:
//  phase 1: per-node projection into pa/pd tables (HBM-bound, 51.2 MB read)
//           pa[n] = (dot(x[n],W[0,0:128]),  dot(x[n],W[1,0:128]))
//           pd[n] = (dot(x[n],W[0,128:256]),dot(x[n],W[1,128:256]))
//  idx prefetch (int4 per 4 edges) issued BEFORE phase 1 completes -> its 5 MB
//           overlaps the proj stream.
//  grid barrier: release fence + agent-scope arrival counter; relaxed spin +
//           one acquire fence. 256 blocks at 1/CU cannot deadlock.
//  phase 2: edge scoring from L2-resident tables: 2x 8B gathers + adds + store.
__global__ __launch_bounds__(NTHR, 2) void fused_predictor_kernel(
    const float* __restrict__ x,     // [N, 128]
    const int*   __restrict__ idx,   // [2, E] int32
    const float* __restrict__ W,     // [2, 256]
    const float* __restrict__ b,     // [2]
    float*       __restrict__ out,   // [E, 2]
    float2*      __restrict__ pa,    // [N] ws
    float2*      __restrict__ pd,    // [N] ws
    unsigned int* __restrict__ counter,  // ws, memset to 0 before launch
    int n_nodes, int n_edges) {
    __shared__ __align__(16) float wlds[4 * 144];  // [4 tables][4 subs][36]

    // ---- stage W into padded LDS (conflict-free b128 reads later) ----
    for (int i = threadIdx.x; i < 512; i += NTHR) {
        int c    = i >> 8;
        int d    = i & 255;
        int half = d >> 7;
        int k    = d & 127;
        int sub  = k >> 5;
        int kk   = k & 31;
        wlds[(half * 2 + c) * 144 + sub * 36 + kk] = W[i];
    }

    // ---- prefetch edge indices (overlaps the HBM-bound proj phase) ----
    const int tglob    = blockIdx.x * NTHR + threadIdx.x;
    const int n_groups = n_edges >> 2;          // groups of 4 edges
    int4 sg[MAX_GRP], dg[MAX_GRP];
    #pragma unroll
    for (int i = 0; i < MAX_GRP; ++i) {
        int g = tglob + i * (NBLK * NTHR);
        if (g < n_groups) {
            sg[i] = *(const int4*)(idx + 4 * g);
            dg[i] = *(const int4*)(idx + n_edges + 4 * g);
        }
    }
    const float b0 = b[0];
    const float b1 = b[1];
    __syncthreads();  // wlds ready

    // ---- phase 1: node projection (quad-split: lane->node l>>2, slice l&3) ----
    const int lane = threadIdx.x & 63;
    const int sub  = lane & 3;
    const int nl   = lane >> 2;
    const int wave = threadIdx.x >> 6;
    const int gwave  = blockIdx.x * 4 + wave;   // 0..1023
    const int stride = NBLK * 4 * 16;           // nodes per grid sweep

    const float* wt = wlds + sub * 36;
    for (int base = gwave * 16; base < n_nodes; base += stride) {
        const int node = base + nl;
        if (node < n_nodes) {
            const float* xb = x + (size_t)node * IN_DIM + sub * 32;
            float a0 = 0.f, a1 = 0.f, d0 = 0.f, d1 = 0.f;
            #pragma unroll
            for (int j = 0; j < 8; ++j) {
                const float4 xv = *(const float4*)(xb + j * 4);
                const float4 w0 = *(const float4*)(wt + 0 * 144 + j * 4);
                const float4 w1 = *(const float4*)(wt + 1 * 144 + j * 4);
                const float4 w2 = *(const float4*)(wt + 2 * 144 + j * 4);
                const float4 w3 = *(const float4*)(wt + 3 * 144 + j * 4);
                a0 += xv.x * w0.x + xv.y * w0.y + xv.z * w0.z + xv.w * w0.w;
                a1 += xv.x * w1.x + xv.y * w1.y + xv.z * w1.z + xv.w * w1.w;
                d0 += xv.x * w2.x + xv.y * w2.y + xv.z * w2.z + xv.w * w2.w;
                d1 += xv.x * w3.x + xv.y * w3.y + xv.z * w3.z + xv.w * w3.w;
            }
            // 2-stage intra-quad butterfly: all quad lanes end with full sums.
            a0 += __shfl_xor(a0, 1, 64);
            a1 += __shfl_xor(a1, 1, 64);
            d0 += __shfl_xor(d0, 1, 64);
            d1 += __shfl_xor(d1, 1, 64);
            a0 += __shfl_xor(a0, 2, 64);
            a1 += __shfl_xor(a1, 2, 64);
            d0 += __shfl_xor(d0, 2, 64);
            d1 += __shfl_xor(d1, 2, 64);
            if (sub == 0) pa[node] = make_float2(a0, a1);
            if (sub == 1) pd[node] = make_float2(d0, d1);
        }
    }

    // ---- grid barrier (device scope) ----
    __syncthreads();  // all waves of this block done with proj
    if (threadIdx.x == 0) {
        __threadfence();  // release: pa/pd stores visible agent-wide
        __hip_atomic_fetch_add(counter, 1u, __ATOMIC_RELEASE, __HIP_MEMORY_SCOPE_AGENT);
        while (__hip_atomic_load(counter, __ATOMIC_RELAXED, __HIP_MEMORY_SCOPE_AGENT)
               < (unsigned)NBLK) {
            __builtin_amdgcn_s_sleep(8);
        }
        __threadfence();  // acquire: invalidate stale cached table lines
    }
    __syncthreads();

    // ---- phase 2: edge scoring (gathers hit L2-resident 1.6 MB tables) ----
    #pragma unroll
    for (int i = 0; i < MAX_GRP; ++i) {
        int g = tglob + i * (NBLK * NTHR);
        if (g < n_groups) {
            const float2 a0 = pa[sg[i].x];
            const float2 a1 = pa[sg[i].y];
            const float2 a2 = pa[sg[i].z];
            const float2 a3 = pa[sg[i].w];
            const float2 q0 = pd[dg[i].x];
            const float2 q1 = pd[dg[i].y];
            const float2 q2 = pd[dg[i].z];
            const float2 q3 = pd[dg[i].w];
            float4 o01, o23;
            o01.x = a0.x + q0.x + b0;
            o01.y = a0.y + q0.y + b1;
            o01.z = a1.x + q1.x + b0;
            o01.w = a1.y + q1.y + b1;
            o23.x = a2.x + q2.x + b0;
            o23.y = a2.y + q2.y + b1;
            o23.z = a3.x + q3.x + b0;
            o23.w = a3.y + q3.y + b1;
            *(float4*)(out + 8 * (size_t)g)     = o01;
            *(float4*)(out + 8 * (size_t)g + 4) = o23;
        }
    }
    // scalar tail (n_edges % 4) — not hit for E=625000 but kept for generality
    if (blockIdx.x == 0 && threadIdx.x < (n_edges & 3)) {
        int e = (n_groups << 2) + threadIdx.x;
        const float2 ps = pa[idx[e]];
        const float2 pq = pd[idx[n_edges + e]];
        out[2 * (size_t)e + 0] = ps.x + pq.x + b0;
        out[2 * (size_t)e + 1] = ps.y + pq.y + b1;
    }
}

extern "C" void kernel_launch(void* const* d_in, const int* in_sizes, int n_in,
                              void* d_out, int out_size, void* d_ws, size_t ws_size,
                              hipStream_t stream) {
    const float* x   = (const float*)d_in[0];   // [N, 128]
    const int*   idx = (const int*)d_in[1];     // [2, E] as int32
    const float* W   = (const float*)d_in[2];   // [2, 256]
    const float* b   = (const float*)d_in[3];   // [2]
    float* out = (float*)d_out;                 // [E, 2] fp32

    const int n_nodes = in_sizes[0] / IN_DIM;   // 100000
    const int n_edges = in_sizes[1] / 2;        // 625000

    // ws layout: [counter (128B slot)] [pa: N float2] [pd: N float2]
    unsigned int* counter = (unsigned int*)d_ws;
    float2* pa = (float2*)((char*)d_ws + 128);
    float2* pd = pa + n_nodes;

    hipMemsetAsync(counter, 0, sizeof(unsigned int), stream);
    fused_predictor_kernel<<<NBLK, NTHR, 0, stream>>>(
        x, idx, W, b, out, pa, pd, counter, n_nodes, n_edges);
}

// Round 5
// 101.454 us; speedup vs baseline: 1.2981x; 1.2981x over previous
//
#include <hip/hip_runtime.h>
#include <hip/hip_bf16.h>

#define IN_DIM 128

// Kernel 1: per-node projection, quad-split layout.
// pa[n] = (dot(x[n], W[0,0:128]),   dot(x[n], W[1,0:128]))    -- src side
// pd[n] = (dot(x[n], W[0,128:256]), dot(x[n], W[1,128:256]))  -- dst side
//
// Lane l -> node (l>>2), dim-slice (l&3)*32..+32. Each lane keeps 4 partial
// dots over its 32-dim slice; reduction is a 2-stage intra-quad butterfly
// (all 4 lanes end with full sums; sub==0 writes pa, sub==1 writes pd).
// W (512 floats) staged once per block into padded LDS (table stride 144,
// sub stride 36 -> conflict-free ds_read_b128 with 16-lane broadcast).
// 1563 blocks -> ~6 blocks/CU: block-level parallelism hides HBM latency
// (the R4 persistent version at 1 block/CU ran at 9% of peak BW).
__global__ __launch_bounds__(256) void node_proj_kernel(
    const float* __restrict__ x,   // [N, 128]
    const float* __restrict__ W,   // [2, 256]
    float2* __restrict__ pa,       // [N] (a0,a1)
    float2* __restrict__ pd,       // [N] (d0,d1)
    int n_nodes) {
    __shared__ __align__(16) float wlds[4 * 144];  // [4 tables][4 subs][36]

    for (int i = threadIdx.x; i < 512; i += 256) {
        int c    = i >> 8;
        int d    = i & 255;
        int half = d >> 7;
        int k    = d & 127;
        int sub  = k >> 5;
        int kk   = k & 31;
        wlds[(half * 2 + c) * 144 + sub * 36 + kk] = W[i];
    }
    __syncthreads();

    const int lane = threadIdx.x & 63;
    const int sub  = lane & 3;        // which 32-dim slice
    const int nl   = lane >> 2;       // node within wave (0..15)
    const int wave = threadIdx.x >> 6;
    const int node = (blockIdx.x * 4 + wave) * 16 + nl;

    if (node < n_nodes) {
        const float* xb = x + (size_t)node * IN_DIM + sub * 32;
        const float* wt = wlds + sub * 36;

        float a0 = 0.f, a1 = 0.f, d0 = 0.f, d1 = 0.f;
        #pragma unroll
        for (int j = 0; j < 8; ++j) {
            const float4 xv = *(const float4*)(xb + j * 4);
            const float4 w0 = *(const float4*)(wt + 0 * 144 + j * 4);
            const float4 w1 = *(const float4*)(wt + 1 * 144 + j * 4);
            const float4 w2 = *(const float4*)(wt + 2 * 144 + j * 4);
            const float4 w3 = *(const float4*)(wt + 3 * 144 + j * 4);
            a0 += xv.x * w0.x + xv.y * w0.y + xv.z * w0.z + xv.w * w0.w;
            a1 += xv.x * w1.x + xv.y * w1.y + xv.z * w1.z + xv.w * w1.w;
            d0 += xv.x * w2.x + xv.y * w2.y + xv.z * w2.z + xv.w * w2.w;
            d1 += xv.x * w3.x + xv.y * w3.y + xv.z * w3.z + xv.w * w3.w;
        }

        // 2-stage intra-quad butterfly: afterwards ALL quad lanes hold sums.
        a0 += __shfl_xor(a0, 1, 64);
        a1 += __shfl_xor(a1, 1, 64);
        d0 += __shfl_xor(d0, 1, 64);
        d1 += __shfl_xor(d1, 1, 64);
        a0 += __shfl_xor(a0, 2, 64);
        a1 += __shfl_xor(a1, 2, 64);
        d0 += __shfl_xor(d0, 2, 64);
        d1 += __shfl_xor(d1, 2, 64);

        if (sub == 0) pa[node] = make_float2(a0, a1);
        if (sub == 1) pd[node] = make_float2(d0, d1);
    }
}

// Kernel 2: per-edge scoring from two 0.8 MB float2 tables (L2/L3-resident).
// 4 edges per thread: int4 index loads, 8x 8B gathers, two float4 stores.
__global__ __launch_bounds__(256) void edge_score_kernel(
    const int* __restrict__ idx,     // [2, E] (src row then dst row), int32
    const float2* __restrict__ pa,   // [N]
    const float2* __restrict__ pd,   // [N]
    const float* __restrict__ b,     // [2]
    float* __restrict__ out,         // [E, 2]
    int n_edges) {
    const int g = blockIdx.x * blockDim.x + threadIdx.x;   // group of 4 edges
    const int n_groups = n_edges >> 2;
    const float b0 = b[0];
    const float b1 = b[1];
    if (g < n_groups) {
        const int4 s = *(const int4*)(idx + 4 * g);
        const int4 d = *(const int4*)(idx + n_edges + 4 * g);
        const float2 a0 = pa[s.x];
        const float2 a1 = pa[s.y];
        const float2 a2 = pa[s.z];
        const float2 a3 = pa[s.w];
        const float2 q0 = pd[d.x];
        const float2 q1 = pd[d.y];
        const float2 q2 = pd[d.z];
        const float2 q3 = pd[d.w];
        float4 o01, o23;
        o01.x = a0.x + q0.x + b0;
        o01.y = a0.y + q0.y + b1;
        o01.z = a1.x + q1.x + b0;
        o01.w = a1.y + q1.y + b1;
        o23.x = a2.x + q2.x + b0;
        o23.y = a2.y + q2.y + b1;
        o23.z = a3.x + q3.x + b0;
        o23.w = a3.y + q3.y + b1;
        *(float4*)(out + 8 * (size_t)g)     = o01;
        *(float4*)(out + 8 * (size_t)g + 4) = o23;
    }
    // scalar tail (n_edges % 4) — not hit for E=625000 but kept for generality
    if (blockIdx.x == 0 && threadIdx.x < (n_edges & 3)) {
        int e = (n_groups << 2) + threadIdx.x;
        const float2 ps = pa[idx[e]];
        const float2 pq = pd[idx[n_edges + e]];
        out[2 * (size_t)e + 0] = ps.x + pq.x + b0;
        out[2 * (size_t)e + 1] = ps.y + pq.y + b1;
    }
}

extern "C" void kernel_launch(void* const* d_in, const int* in_sizes, int n_in,
                              void* d_out, int out_size, void* d_ws, size_t ws_size,
                              hipStream_t stream) {
    const float* x   = (const float*)d_in[0];   // [N, 128]
    const int*   idx = (const int*)d_in[1];     // [2, E] as int32
    const float* W   = (const float*)d_in[2];   // [2, 256]
    const float* b   = (const float*)d_in[3];   // [2]
    float* out = (float*)d_out;                 // [E, 2] fp32

    const int n_nodes = in_sizes[0] / IN_DIM;   // 100000
    const int n_edges = in_sizes[1] / 2;        // 625000

    float2* pa = (float2*)d_ws;                       // 800 KB
    float2* pd = pa + n_nodes;                        // 800 KB

    // Kernel 1: 64 nodes per 256-thread block (16 per wave).
    const int blocks1 = (n_nodes + 63) / 64;
    node_proj_kernel<<<blocks1, 256, 0, stream>>>(x, W, pa, pd, n_nodes);

    // Kernel 2: four edges per thread.
    const int n_groups = n_edges / 4;
    const int blocks2 = (n_groups + 255) / 256;
    edge_score_kernel<<<blocks2, 256, 0, stream>>>(idx, pa, pd, b, out, n_edges);
}